// Round 1
// baseline (656.252 us; speedup 1.0000x reference)
//
#include <hip/hip_runtime.h>

typedef unsigned int uint;
typedef unsigned short ushort;
typedef __attribute__((ext_vector_type(4))) float f32x4;
typedef __attribute__((ext_vector_type(8))) __bf16 bf16x8;

#define MFMA16(a,b,c) __builtin_amdgcn_mfma_f32_16x16x32_bf16(a,b,c,0,0,0)

__device__ __forceinline__ ushort f2bf(float f){
  uint u = __float_as_uint(f);
  u += 0x7fffu + ((u>>16)&1u);
  return (ushort)(u>>16);
}
__device__ __forceinline__ float bf2f(ushort s){ return __uint_as_float(((uint)s)<<16); }
__device__ __forceinline__ uint packbf2(float a, float b){ return (uint)f2bf(a) | ((uint)f2bf(b)<<16); }

// ---------------- weight transpose: W[K][N] fp32 -> WT[N][K] bf16 ----------------
__global__ __launch_bounds__(256) void wt_kernel(const float* __restrict__ W,
    ushort* __restrict__ WT, int K, int N){
  int e = blockIdx.x*256 + threadIdx.x;
  if (e >= K*N) return;
  int n = e % N, k = e / N;
  WT[(size_t)n*K + k] = f2bf(W[(size_t)k*N + n]);
}

// ---------------- generic bf16 MFMA GEMM: C = A[M,K] * Bt[N,K]^T + bias ----------------
template<bool A_F32, bool OUT_F32>
__global__ __launch_bounds__(256) void gemm_bt(const void* __restrict__ Av,
    const ushort* __restrict__ Bt, const float* __restrict__ bias,
    void* __restrict__ Cv, int M, int N, int K){
  __shared__ ushort As[64*48];   // 64 rows x (32 k + 16 pad), stride 96B (16B-mult)
  __shared__ ushort Bs[64*48];
  const int tid = threadIdx.x;
  const int m0 = blockIdx.y<<6, n0 = blockIdx.x<<6;
  const int wave = tid>>6, lane = tid&63;
  const int wr = wave&1, wc = wave>>1;
  const int fl = lane&15, quad = lane>>4;
  f32x4 acc[2][2] = {};
  const int srow = tid>>2, sk = (tid&3)<<3;
  for (int k0 = 0; k0 < K; k0 += 32){
    if (A_F32){
      const float* A = (const float*)Av;
      const float4* pa = reinterpret_cast<const float4*>(A + (size_t)(m0+srow)*K + k0 + sk);
      float4 v0 = pa[0], v1 = pa[1];
      uint4 pk = make_uint4(packbf2(v0.x,v0.y), packbf2(v0.z,v0.w),
                            packbf2(v1.x,v1.y), packbf2(v1.z,v1.w));
      *reinterpret_cast<uint4*>(&As[srow*48 + sk]) = pk;
    } else {
      const ushort* A = (const ushort*)Av;
      *reinterpret_cast<uint4*>(&As[srow*48 + sk]) =
          *reinterpret_cast<const uint4*>(A + (size_t)(m0+srow)*K + k0 + sk);
    }
    *reinterpret_cast<uint4*>(&Bs[srow*48 + sk]) =
        *reinterpret_cast<const uint4*>(Bt + (size_t)(n0+srow)*K + k0 + sk);
    __syncthreads();
    bf16x8 a0 = *reinterpret_cast<const bf16x8*>(&As[(32*wr      + fl)*48 + quad*8]);
    bf16x8 a1 = *reinterpret_cast<const bf16x8*>(&As[(32*wr + 16 + fl)*48 + quad*8]);
    bf16x8 b0 = *reinterpret_cast<const bf16x8*>(&Bs[(32*wc      + fl)*48 + quad*8]);
    bf16x8 b1 = *reinterpret_cast<const bf16x8*>(&Bs[(32*wc + 16 + fl)*48 + quad*8]);
    acc[0][0] = MFMA16(a0,b0,acc[0][0]);
    acc[0][1] = MFMA16(a0,b1,acc[0][1]);
    acc[1][0] = MFMA16(a1,b0,acc[1][0]);
    acc[1][1] = MFMA16(a1,b1,acc[1][1]);
    __syncthreads();
  }
  #pragma unroll
  for (int t=0;t<2;++t)
  #pragma unroll
  for (int u=0;u<2;++u){
    #pragma unroll
    for (int r=0;r<4;++r){
      // C/D layout (m89-verified): col = lane&15, row = quad*4 + reg
      int row = m0 + 32*wr + 16*t + quad*4 + r;
      int col = n0 + 32*wc + 16*u + fl;
      float vv = acc[t][u][r] + bias[col];
      if (OUT_F32) ((float*)Cv)[(size_t)row*N + col] = vv;
      else         ((ushort*)Cv)[(size_t)row*N + col] = f2bf(vv);
    }
  }
}

// ---------------- vp [B*S, 512] bf16 -> vT [(b*8+h)*64 + d][1024 k] bf16 ----------------
__global__ __launch_bounds__(256) void vtrans(const ushort* __restrict__ vp,
    ushort* __restrict__ vT){
  __shared__ ushort tile[64*72];
  const int bh = blockIdx.y;            // b*8 + h
  const int b = bh>>3, h = bh&7;
  const int k0 = blockIdx.x<<6;
  const int tid = threadIdx.x;
  #pragma unroll
  for (int i=0;i<2;++i){
    int c = tid + (i<<8);
    int row = c>>3, ch = (c&7)<<3;
    uint4 v = *reinterpret_cast<const uint4*>(
        vp + ((size_t)(b*1024 + k0 + row)<<9) + (h<<6) + ch);
    *reinterpret_cast<uint4*>(&tile[row*72 + ch]) = v;
  }
  __syncthreads();
  #pragma unroll
  for (int i=0;i<2;++i){
    int c = tid + (i<<8);
    int d = c>>3, sc = (c&7)<<3;
    ushort t0 = tile[(sc+0)*72 + d], t1 = tile[(sc+1)*72 + d];
    ushort t2 = tile[(sc+2)*72 + d], t3 = tile[(sc+3)*72 + d];
    ushort t4 = tile[(sc+4)*72 + d], t5 = tile[(sc+5)*72 + d];
    ushort t6 = tile[(sc+6)*72 + d], t7 = tile[(sc+7)*72 + d];
    uint4 pk = make_uint4((uint)t0|((uint)t1<<16), (uint)t2|((uint)t3<<16),
                          (uint)t4|((uint)t5<<16), (uint)t6|((uint)t7<<16));
    *reinterpret_cast<uint4*>(vT + (((size_t)bh<<6) + d)*1024 + k0 + sc) = pk;
  }
}

// ---------------- xl[b,h,q,k] = bf16( 0.5 * sum_f xdiff[b,q,k,f]*xh[b,q,h,f] ) ----------------
__global__ __launch_bounds__(256) void xl_kernel(const float* __restrict__ xdiff,
    const ushort* __restrict__ xb, ushort* __restrict__ xl){
  const int bq = blockIdx.x;            // b*1024 + q
  const int b = bq>>10, q = bq&1023;
  __shared__ float sx[8][16];
  const int tid = threadIdx.x;
  if (tid < 128) sx[tid>>4][tid&15] = bf2f(xb[(size_t)bq*128 + tid]);
  __syncthreads();
  const float* xd = xdiff + (size_t)bq*16384;
  #pragma unroll
  for (int i=0;i<4;++i){
    int k = tid + (i<<8);
    const float4* p = reinterpret_cast<const float4*>(xd + (size_t)k*16);
    float4 v0 = p[0], v1 = p[1], v2 = p[2], v3 = p[3];
    #pragma unroll
    for (int h=0; h<8; ++h){
      const float4* s = reinterpret_cast<const float4*>(&sx[h][0]);
      float4 s0=s[0], s1=s[1], s2=s[2], s3=s[3];
      float a = v0.x*s0.x + v0.y*s0.y + v0.z*s0.z + v0.w*s0.w
              + v1.x*s1.x + v1.y*s1.y + v1.z*s1.z + v1.w*s1.w
              + v2.x*s2.x + v2.y*s2.y + v2.z*s2.z + v2.w*s2.w
              + v3.x*s3.x + v3.y*s3.y + v3.z*s3.z + v3.w*s3.w;
      xl[(((size_t)((b<<3)+h)<<10) + q)*1024 + k] = f2bf(0.5f*a);
    }
  }
}

// ---------------- fused attention: logits -> softmax -> attn out + PV ----------------
// block = (qtile of 32 rows, h, b); 256 threads = 4 waves (wr = row-half, wc = col-half)
__global__ __launch_bounds__(256) void attn_kernel(const ushort* __restrict__ qp,
    const ushort* __restrict__ kp, const ushort* __restrict__ vT,
    const ushort* __restrict__ xl, float* __restrict__ attn, ushort* __restrict__ outc){
  __shared__ ushort s_p[32*1024];       // 64 KB, XOR-swizzled by (row&7) per 8-elem chunk
  const int qt = blockIdx.x, h = blockIdx.y, b = blockIdx.z;
  const int q0 = qt<<5;
  const int tid = threadIdx.x, lane = tid&63, wave = tid>>6;
  const int wr = wave&1, wc = wave>>1;
  const int fl = lane&15, quad = lane>>4;
  const size_t bS = (size_t)b<<10;
  const int bh = (b<<3) + h;

  // Q fragments (A-operand: row = lane&15, k = quad*8+j), straight from global
  bf16x8 aq[2];
  #pragma unroll
  for (int s=0;s<2;++s)
    aq[s] = *reinterpret_cast<const bf16x8*>(
        qp + ((bS + q0 + (wr<<4) + fl)<<9) + (h<<6) + (s<<5) + (quad<<3));

  // ---- QK^T: 16 key-tiles of 64 ----
  for (int kt=0; kt<16; ++kt){
    f32x4 acc0 = {}, acc1 = {};
    #pragma unroll
    for (int s=0;s<2;++s){
      const ushort* kbase = kp + ((bS + (kt<<6) + (wc<<5) + fl)<<9) + (h<<6) + (s<<5) + (quad<<3);
      bf16x8 b0 = *reinterpret_cast<const bf16x8*>(kbase);
      bf16x8 b1 = *reinterpret_cast<const bf16x8*>(kbase + (16<<9));
      acc0 = MFMA16(aq[s], b0, acc0);
      acc1 = MFMA16(aq[s], b1, acc1);
    }
    #pragma unroll
    for (int u=0;u<2;++u){
      f32x4 a = u ? acc1 : acc0;
      #pragma unroll
      for (int r=0;r<4;++r){
        int row = (wr<<4) + (quad<<2) + r;
        int col = (kt<<6) + (wc<<5) + (u<<4) + fl;
        int chunk = (col>>3) ^ (row&7);
        s_p[(row<<10) + (chunk<<3) + (col&7)] = f2bf(a[r]*0.125f);
      }
    }
  }
  __syncthreads();

  // ---- softmax: 8 threads per row, shuffle reductions ----
  const int r = tid>>3, seg = tid&7, swz = r&7;
  const ushort* xrow = xl + (((size_t)bh<<10) + q0 + r)*1024;
  float* arow = attn + (((size_t)bh<<10) + q0 + r)*1024;
  float mx = -3.0e38f;
  for (int cc=0; cc<16; ++cc){         // pass 1: add xl bias, track max
    int chunk = (seg<<4) + cc;
    uint4 lv = *reinterpret_cast<uint4*>(&s_p[(r<<10) + ((chunk^swz)<<3)]);
    uint4 xv = *reinterpret_cast<const uint4*>(xrow + (chunk<<3));
    float f0 = bf2f(lv.x&0xffff)+bf2f(xv.x&0xffff), f1 = bf2f(lv.x>>16)+bf2f(xv.x>>16);
    float f2 = bf2f(lv.y&0xffff)+bf2f(xv.y&0xffff), f3 = bf2f(lv.y>>16)+bf2f(xv.y>>16);
    float f4 = bf2f(lv.z&0xffff)+bf2f(xv.z&0xffff), f5 = bf2f(lv.z>>16)+bf2f(xv.z>>16);
    float f6 = bf2f(lv.w&0xffff)+bf2f(xv.w&0xffff), f7 = bf2f(lv.w>>16)+bf2f(xv.w>>16);
    mx = fmaxf(mx, fmaxf(fmaxf(fmaxf(f0,f1),fmaxf(f2,f3)), fmaxf(fmaxf(f4,f5),fmaxf(f6,f7))));
    uint4 pk = make_uint4(packbf2(f0,f1), packbf2(f2,f3), packbf2(f4,f5), packbf2(f6,f7));
    *reinterpret_cast<uint4*>(&s_p[(r<<10) + ((chunk^swz)<<3)]) = pk;
  }
  #pragma unroll
  for (int d=1; d<8; d<<=1) mx = fmaxf(mx, __shfl_xor(mx, d));
  float sum = 0.f;
  for (int cc=0; cc<16; ++cc){         // pass 2: exp, bf16-round, sum
    int chunk = (seg<<4) + cc;
    uint4 lv = *reinterpret_cast<uint4*>(&s_p[(r<<10) + ((chunk^swz)<<3)]);
    ushort u0 = f2bf(__expf(bf2f(lv.x&0xffff)-mx)), u1 = f2bf(__expf(bf2f(lv.x>>16)-mx));
    ushort u2 = f2bf(__expf(bf2f(lv.y&0xffff)-mx)), u3 = f2bf(__expf(bf2f(lv.y>>16)-mx));
    ushort u4 = f2bf(__expf(bf2f(lv.z&0xffff)-mx)), u5 = f2bf(__expf(bf2f(lv.z>>16)-mx));
    ushort u6 = f2bf(__expf(bf2f(lv.w&0xffff)-mx)), u7 = f2bf(__expf(bf2f(lv.w>>16)-mx));
    sum += bf2f(u0)+bf2f(u1)+bf2f(u2)+bf2f(u3)+bf2f(u4)+bf2f(u5)+bf2f(u6)+bf2f(u7);
    uint4 pk = make_uint4((uint)u0|((uint)u1<<16), (uint)u2|((uint)u3<<16),
                          (uint)u4|((uint)u5<<16), (uint)u6|((uint)u7<<16));
    *reinterpret_cast<uint4*>(&s_p[(r<<10) + ((chunk^swz)<<3)]) = pk;
  }
  #pragma unroll
  for (int d=1; d<8; d<<=1) sum += __shfl_xor(sum, d);
  float inv = 1.f/sum;
  for (int cc=0; cc<16; ++cc){         // pass 3: write attn fp32, keep normalized bf16 in LDS
    int chunk = (seg<<4) + cc;
    uint4 lv = *reinterpret_cast<uint4*>(&s_p[(r<<10) + ((chunk^swz)<<3)]);
    float o0 = bf2f(lv.x&0xffff)*inv, o1 = bf2f(lv.x>>16)*inv;
    float o2 = bf2f(lv.y&0xffff)*inv, o3 = bf2f(lv.y>>16)*inv;
    float o4 = bf2f(lv.z&0xffff)*inv, o5 = bf2f(lv.z>>16)*inv;
    float o6 = bf2f(lv.w&0xffff)*inv, o7 = bf2f(lv.w>>16)*inv;
    *reinterpret_cast<float4*>(arow + (chunk<<3))     = make_float4(o0,o1,o2,o3);
    *reinterpret_cast<float4*>(arow + (chunk<<3) + 4) = make_float4(o4,o5,o6,o7);
    uint4 pk = make_uint4(packbf2(o0,o1), packbf2(o2,o3), packbf2(o4,o5), packbf2(o6,o7));
    *reinterpret_cast<uint4*>(&s_p[(r<<10) + ((chunk^swz)<<3)]) = pk;
  }
  __syncthreads();

  // ---- PV: out[32 q][64 d] = attn * V, barrier-free (s_p read-only, vT from global) ----
  f32x4 o0 = {}, o1 = {};
  const int ar = (wr<<4) + fl;         // a-frag row
  const int aswz = ar & 7;
  for (int kt=0; kt<16; ++kt){
    #pragma unroll
    for (int s=0;s<2;++s){
      int chunk = (kt<<3) + (s<<2) + quad;
      bf16x8 af = *reinterpret_cast<const bf16x8*>(&s_p[(ar<<10) + ((chunk^aswz)<<3)]);
      const ushort* vbase = vT + (((size_t)bh<<6) + (wc<<5) + fl)*1024 + (kt<<6) + (s<<5) + (quad<<3);
      bf16x8 b0 = *reinterpret_cast<const bf16x8*>(vbase);
      bf16x8 b1 = *reinterpret_cast<const bf16x8*>(vbase + (16<<10));
      o0 = MFMA16(af, b0, o0);
      o1 = MFMA16(af, b1, o1);
    }
  }
  #pragma unroll
  for (int u=0;u<2;++u){
    f32x4 a = u ? o1 : o0;
    #pragma unroll
    for (int r4=0;r4<4;++r4){
      int row = (wr<<4) + (quad<<2) + r4;
      int col = (wc<<5) + (u<<4) + fl;
      outc[((bS + q0 + row)<<9) + (h<<6) + col] = f2bf(a[r4]);
    }
  }
}

extern "C" void kernel_launch(void* const* d_in, const int* in_sizes, int n_in,
                              void* d_out, int out_size, void* d_ws, size_t ws_size,
                              hipStream_t stream){
  (void)in_sizes; (void)n_in; (void)out_size; (void)ws_size;
  const float* q  = (const float*)d_in[0];
  const float* k  = (const float*)d_in[1];
  const float* v  = (const float*)d_in[2];
  const float* xd = (const float*)d_in[3];
  const float* Wq = (const float*)d_in[4];  const float* bq = (const float*)d_in[5];
  const float* Wk = (const float*)d_in[6];  const float* bk = (const float*)d_in[7];
  const float* Wv = (const float*)d_in[8];  const float* bv = (const float*)d_in[9];
  const float* Wx = (const float*)d_in[10]; const float* bx = (const float*)d_in[11];
  const float* Wo = (const float*)d_in[12]; const float* bo = (const float*)d_in[13];
  char* ws = (char*)d_ws;
  const size_t MB = 1u<<20;
  ushort* qp  = (ushort*)(ws);                 // [4096][512] bf16  (4 MB)
  ushort* kp  = (ushort*)(ws + 4*MB);
  ushort* vp  = (ushort*)(ws + 8*MB);
  ushort* vT  = (ushort*)(ws + 12*MB);         // [32*64][1024] bf16
  ushort* xb  = (ushort*)(ws + 16*MB);         // [4096][128] bf16  (1 MB)
  ushort* xl  = (ushort*)(ws + 17*MB);         // [4,8,1024,1024] bf16 (64 MB)
  ushort* oc  = (ushort*)(ws + 81*MB);         // [4096][512] bf16
  ushort* WqT = (ushort*)(ws + 85*MB);
  ushort* WkT = (ushort*)(ws + 85*MB + 1*524288);
  ushort* WvT = (ushort*)(ws + 85*MB + 2*524288);
  ushort* WoT = (ushort*)(ws + 85*MB + 3*524288);
  ushort* WxT = (ushort*)(ws + 85*MB + 4*524288);
  float* out0 = (float*)d_out;                 // [4,1024,512] fp32
  float* attn = (float*)d_out + 2097152;       // [4,8,1024,1024] fp32

  wt_kernel<<<1024, 256, 0, stream>>>(Wq, WqT, 512, 512);
  wt_kernel<<<1024, 256, 0, stream>>>(Wk, WkT, 512, 512);
  wt_kernel<<<1024, 256, 0, stream>>>(Wv, WvT, 512, 512);
  wt_kernel<<<1024, 256, 0, stream>>>(Wo, WoT, 512, 512);
  wt_kernel<<< 256, 256, 0, stream>>>(Wx, WxT, 512, 128);

  gemm_bt<true,false><<<dim3(8,64), 256, 0, stream>>>(q, WqT, bq, qp, 4096, 512, 512);
  gemm_bt<true,false><<<dim3(8,64), 256, 0, stream>>>(k, WkT, bk, kp, 4096, 512, 512);
  gemm_bt<true,false><<<dim3(8,64), 256, 0, stream>>>(v, WvT, bv, vp, 4096, 512, 512);
  gemm_bt<false,false><<<dim3(2,64), 256, 0, stream>>>(qp, WxT, bx, xb, 4096, 128, 512);

  vtrans<<<dim3(16,32), 256, 0, stream>>>(vp, vT);
  xl_kernel<<<4096, 256, 0, stream>>>(xd, xb, xl);
  attn_kernel<<<dim3(32,8,4), 256, 0, stream>>>(qp, kp, vT, xl, attn, oc);
  gemm_bt<false,true><<<dim3(8,64), 256, 0, stream>>>(oc, WoT, bo, out0, 4096, 512, 512);
}

// Round 2
// 611.831 us; speedup vs baseline: 1.0726x; 1.0726x over previous
//
#include <hip/hip_runtime.h>

typedef unsigned int uint;
typedef unsigned short ushort;
typedef __attribute__((ext_vector_type(4))) float f32x4;
typedef __attribute__((ext_vector_type(8))) __bf16 bf16x8;

#define MFMA16(a,b,c) __builtin_amdgcn_mfma_f32_16x16x32_bf16(a,b,c,0,0,0)

__device__ __forceinline__ ushort f2bf(float f){
  uint u = __float_as_uint(f);
  u += 0x7fffu + ((u>>16)&1u);
  return (ushort)(u>>16);
}
__device__ __forceinline__ float bf2f(ushort s){ return __uint_as_float(((uint)s)<<16); }
__device__ __forceinline__ uint packbf2(float a, float b){ return (uint)f2bf(a) | ((uint)f2bf(b)<<16); }

// ---------------- tiled weight transpose: W[K][N] fp32 -> WT[N][K] bf16 ----------------
// 64x64 tile; bf16 stored in 4B LDS slots, stride 65 words -> phase-2 column gather is ~2-way.
__global__ __launch_bounds__(256) void wt_kernel(const float* __restrict__ W,
    ushort* __restrict__ WT, int K, int N){
  __shared__ uint tile[64*65];
  const int k0 = blockIdx.y<<6, n0 = blockIdx.x<<6;
  const int tid = threadIdx.x;
  {
    const int row = tid>>4, c4 = (tid&15)<<2;
    #pragma unroll
    for (int i=0;i<4;++i){
      int r = row + (i<<4);
      float4 v = *reinterpret_cast<const float4*>(W + (size_t)(k0+r)*N + n0 + c4);
      tile[r*65 + c4    ] = f2bf(v.x);
      tile[r*65 + c4 + 1] = f2bf(v.y);
      tile[r*65 + c4 + 2] = f2bf(v.z);
      tile[r*65 + c4 + 3] = f2bf(v.w);
    }
  }
  __syncthreads();
  {
    const int n = tid>>3, k8 = (tid&7)<<3;
    #pragma unroll
    for (int j=0;j<2;++j){
      int nn = n + (j<<5);
      ushort t0=(ushort)tile[(k8+0)*65+nn], t1=(ushort)tile[(k8+1)*65+nn];
      ushort t2=(ushort)tile[(k8+2)*65+nn], t3=(ushort)tile[(k8+3)*65+nn];
      ushort t4=(ushort)tile[(k8+4)*65+nn], t5=(ushort)tile[(k8+5)*65+nn];
      ushort t6=(ushort)tile[(k8+6)*65+nn], t7=(ushort)tile[(k8+7)*65+nn];
      uint4 pk = make_uint4((uint)t0|((uint)t1<<16), (uint)t2|((uint)t3<<16),
                            (uint)t4|((uint)t5<<16), (uint)t6|((uint)t7<<16));
      *reinterpret_cast<uint4*>(WT + (size_t)(n0+nn)*K + k0 + k8) = pk;
    }
  }
}

// ---------------- generic bf16 MFMA GEMM: C = A[M,K] * Bt[N,K]^T + bias ----------------
template<bool A_F32, bool OUT_F32>
__global__ __launch_bounds__(256) void gemm_bt(const void* __restrict__ Av,
    const ushort* __restrict__ Bt, const float* __restrict__ bias,
    void* __restrict__ Cv, int M, int N, int K){
  __shared__ ushort As[64*48];   // 64 rows x (32 k + 16 pad), stride 96B (16B-mult)
  __shared__ ushort Bs[64*48];
  const int tid = threadIdx.x;
  const int m0 = blockIdx.y<<6, n0 = blockIdx.x<<6;
  const int wave = tid>>6, lane = tid&63;
  const int wr = wave&1, wc = wave>>1;
  const int fl = lane&15, quad = lane>>4;
  f32x4 acc[2][2] = {};
  const int srow = tid>>2, sk = (tid&3)<<3;
  for (int k0 = 0; k0 < K; k0 += 32){
    if (A_F32){
      const float* A = (const float*)Av;
      const float4* pa = reinterpret_cast<const float4*>(A + (size_t)(m0+srow)*K + k0 + sk);
      float4 v0 = pa[0], v1 = pa[1];
      uint4 pk = make_uint4(packbf2(v0.x,v0.y), packbf2(v0.z,v0.w),
                            packbf2(v1.x,v1.y), packbf2(v1.z,v1.w));
      *reinterpret_cast<uint4*>(&As[srow*48 + sk]) = pk;
    } else {
      const ushort* A = (const ushort*)Av;
      *reinterpret_cast<uint4*>(&As[srow*48 + sk]) =
          *reinterpret_cast<const uint4*>(A + (size_t)(m0+srow)*K + k0 + sk);
    }
    *reinterpret_cast<uint4*>(&Bs[srow*48 + sk]) =
        *reinterpret_cast<const uint4*>(Bt + (size_t)(n0+srow)*K + k0 + sk);
    __syncthreads();
    bf16x8 a0 = *reinterpret_cast<const bf16x8*>(&As[(32*wr      + fl)*48 + quad*8]);
    bf16x8 a1 = *reinterpret_cast<const bf16x8*>(&As[(32*wr + 16 + fl)*48 + quad*8]);
    bf16x8 b0 = *reinterpret_cast<const bf16x8*>(&Bs[(32*wc      + fl)*48 + quad*8]);
    bf16x8 b1 = *reinterpret_cast<const bf16x8*>(&Bs[(32*wc + 16 + fl)*48 + quad*8]);
    acc[0][0] = MFMA16(a0,b0,acc[0][0]);
    acc[0][1] = MFMA16(a0,b1,acc[0][1]);
    acc[1][0] = MFMA16(a1,b0,acc[1][0]);
    acc[1][1] = MFMA16(a1,b1,acc[1][1]);
    __syncthreads();
  }
  #pragma unroll
  for (int t=0;t<2;++t)
  #pragma unroll
  for (int u=0;u<2;++u){
    #pragma unroll
    for (int r=0;r<4;++r){
      int row = m0 + 32*wr + 16*t + quad*4 + r;
      int col = n0 + 32*wc + 16*u + fl;
      float vv = acc[t][u][r] + bias[col];
      if (OUT_F32) ((float*)Cv)[(size_t)row*N + col] = vv;
      else         ((ushort*)Cv)[(size_t)row*N + col] = f2bf(vv);
    }
  }
}

// ---------------- vp [B*S, 512] bf16 -> vT [(b*8+h)*64 + d][1024 k] bf16 ----------------
__global__ __launch_bounds__(256) void vtrans(const ushort* __restrict__ vp,
    ushort* __restrict__ vT){
  __shared__ ushort tile[64*72];
  const int bh = blockIdx.y;            // b*8 + h
  const int b = bh>>3, h = bh&7;
  const int k0 = blockIdx.x<<6;
  const int tid = threadIdx.x;
  #pragma unroll
  for (int i=0;i<2;++i){
    int c = tid + (i<<8);
    int row = c>>3, ch = (c&7)<<3;
    uint4 v = *reinterpret_cast<const uint4*>(
        vp + ((size_t)(b*1024 + k0 + row)<<9) + (h<<6) + ch);
    *reinterpret_cast<uint4*>(&tile[row*72 + ch]) = v;
  }
  __syncthreads();
  #pragma unroll
  for (int i=0;i<2;++i){
    int c = tid + (i<<8);
    int d = c>>3, sc = (c&7)<<3;
    ushort t0 = tile[(sc+0)*72 + d], t1 = tile[(sc+1)*72 + d];
    ushort t2 = tile[(sc+2)*72 + d], t3 = tile[(sc+3)*72 + d];
    ushort t4 = tile[(sc+4)*72 + d], t5 = tile[(sc+5)*72 + d];
    ushort t6 = tile[(sc+6)*72 + d], t7 = tile[(sc+7)*72 + d];
    uint4 pk = make_uint4((uint)t0|((uint)t1<<16), (uint)t2|((uint)t3<<16),
                          (uint)t4|((uint)t5<<16), (uint)t6|((uint)t7<<16));
    *reinterpret_cast<uint4*>(vT + (((size_t)bh<<6) + d)*1024 + k0 + sc) = pk;
  }
}

// ---------------- xl[b,h,q,k] = bf16( 0.5 * sum_f xdiff[b,q,k,f]*xh[b,q,h,f] ) ----------------
__global__ __launch_bounds__(256) void xl_kernel(const float* __restrict__ xdiff,
    const ushort* __restrict__ xb, ushort* __restrict__ xl){
  const int bq = blockIdx.x;            // b*1024 + q
  const int b = bq>>10, q = bq&1023;
  __shared__ float sx[8][16];
  const int tid = threadIdx.x;
  if (tid < 128) sx[tid>>4][tid&15] = bf2f(xb[(size_t)bq*128 + tid]);
  __syncthreads();
  const float* xd = xdiff + (size_t)bq*16384;
  #pragma unroll
  for (int i=0;i<4;++i){
    int k = tid + (i<<8);
    const float4* p = reinterpret_cast<const float4*>(xd + (size_t)k*16);
    float4 v0 = p[0], v1 = p[1], v2 = p[2], v3 = p[3];
    #pragma unroll
    for (int h=0; h<8; ++h){
      const float4* s = reinterpret_cast<const float4*>(&sx[h][0]);
      float4 s0=s[0], s1=s[1], s2=s[2], s3=s[3];
      float a = v0.x*s0.x + v0.y*s0.y + v0.z*s0.z + v0.w*s0.w
              + v1.x*s1.x + v1.y*s1.y + v1.z*s1.z + v1.w*s1.w
              + v2.x*s2.x + v2.y*s2.y + v2.z*s2.z + v2.w*s2.w
              + v3.x*s3.x + v3.y*s3.y + v3.z*s3.z + v3.w*s3.w;
      xl[(((size_t)((b<<3)+h)<<10) + q)*1024 + k] = f2bf(0.5f*a);
    }
  }
}

// ---------------- fused attention: logits -> softmax -> attn out + PV ----------------
// 512 threads = 8 waves: wr = wave&1 (q-half), wc = wave>>1 in 0..3 (16-col strip).
// s_p swizzle: physical chunk = logical chunk ^ ((row>>1)&7)  (8-elem chunks).
__global__ __launch_bounds__(512) void attn_kernel(const ushort* __restrict__ qp,
    const ushort* __restrict__ kp, const ushort* __restrict__ vT,
    const ushort* __restrict__ xl, float* __restrict__ attn, ushort* __restrict__ outc){
  __shared__ ushort s_p[32*1024];       // 64 KB
  const int qt = blockIdx.x, h = blockIdx.y, b = blockIdx.z;
  const int q0 = qt<<5;
  const int tid = threadIdx.x, lane = tid&63, wave = tid>>6;
  const int wr = wave&1, wc = wave>>1;  // wc in 0..3
  const int fl = lane&15, quad = lane>>4;
  const size_t bS = (size_t)b<<10;
  const int bh = (b<<3) + h;

  // Q fragments (A-operand: m = lane&15, k = quad*8+j), straight from global
  bf16x8 aq[2];
  #pragma unroll
  for (int s=0;s<2;++s)
    aq[s] = *reinterpret_cast<const bf16x8*>(
        qp + ((bS + q0 + (wr<<4) + fl)<<9) + (h<<6) + (s<<5) + (quad<<3));

  // ---- QK^T: 16 key-tiles of 64; each wave covers a 16-col strip ----
  for (int kt=0; kt<16; ++kt){
    f32x4 acc = {};
    #pragma unroll
    for (int s=0;s<2;++s){
      bf16x8 bf = *reinterpret_cast<const bf16x8*>(
          kp + ((bS + (kt<<6) + (wc<<4) + fl)<<9) + (h<<6) + (s<<5) + (quad<<3));
      acc = MFMA16(aq[s], bf, acc);
    }
    #pragma unroll
    for (int r=0;r<4;++r){
      int row = (wr<<4) + (quad<<2) + r;
      int col = (kt<<6) + (wc<<4) + fl;
      int chunk = (col>>3) ^ ((row>>1)&7);
      s_p[(row<<10) + (chunk<<3) + (col&7)] = f2bf(acc[r]*0.125f);
    }
  }
  __syncthreads();

  // ---- softmax: 16 threads per row, shuffle reductions over 16 lanes ----
  const int r = tid>>4, seg = tid&15, swz = (r>>1)&7;
  const ushort* xrow = xl + (((size_t)bh<<10) + q0 + r)*1024;
  float* arow = attn + (((size_t)bh<<10) + q0 + r)*1024;
  float mx = -3.0e38f;
  for (int cc=0; cc<8; ++cc){          // pass 1: add xl bias, track max
    int chunk = (cc<<4) + seg;
    uint4 lv = *reinterpret_cast<uint4*>(&s_p[(r<<10) + ((chunk^swz)<<3)]);
    uint4 xv = *reinterpret_cast<const uint4*>(xrow + (chunk<<3));
    float f0 = bf2f(lv.x&0xffff)+bf2f(xv.x&0xffff), f1 = bf2f(lv.x>>16)+bf2f(xv.x>>16);
    float f2 = bf2f(lv.y&0xffff)+bf2f(xv.y&0xffff), f3 = bf2f(lv.y>>16)+bf2f(xv.y>>16);
    float f4 = bf2f(lv.z&0xffff)+bf2f(xv.z&0xffff), f5 = bf2f(lv.z>>16)+bf2f(xv.z>>16);
    float f6 = bf2f(lv.w&0xffff)+bf2f(xv.w&0xffff), f7 = bf2f(lv.w>>16)+bf2f(xv.w>>16);
    mx = fmaxf(mx, fmaxf(fmaxf(fmaxf(f0,f1),fmaxf(f2,f3)), fmaxf(fmaxf(f4,f5),fmaxf(f6,f7))));
    uint4 pk = make_uint4(packbf2(f0,f1), packbf2(f2,f3), packbf2(f4,f5), packbf2(f6,f7));
    *reinterpret_cast<uint4*>(&s_p[(r<<10) + ((chunk^swz)<<3)]) = pk;
  }
  #pragma unroll
  for (int d=1; d<16; d<<=1) mx = fmaxf(mx, __shfl_xor(mx, d));
  float sum = 0.f;
  for (int cc=0; cc<8; ++cc){          // pass 2: exp, bf16-round, sum
    int chunk = (cc<<4) + seg;
    uint4 lv = *reinterpret_cast<uint4*>(&s_p[(r<<10) + ((chunk^swz)<<3)]);
    ushort u0 = f2bf(__expf(bf2f(lv.x&0xffff)-mx)), u1 = f2bf(__expf(bf2f(lv.x>>16)-mx));
    ushort u2 = f2bf(__expf(bf2f(lv.y&0xffff)-mx)), u3 = f2bf(__expf(bf2f(lv.y>>16)-mx));
    ushort u4 = f2bf(__expf(bf2f(lv.z&0xffff)-mx)), u5 = f2bf(__expf(bf2f(lv.z>>16)-mx));
    ushort u6 = f2bf(__expf(bf2f(lv.w&0xffff)-mx)), u7 = f2bf(__expf(bf2f(lv.w>>16)-mx));
    sum += bf2f(u0)+bf2f(u1)+bf2f(u2)+bf2f(u3)+bf2f(u4)+bf2f(u5)+bf2f(u6)+bf2f(u7);
    uint4 pk = make_uint4((uint)u0|((uint)u1<<16), (uint)u2|((uint)u3<<16),
                          (uint)u4|((uint)u5<<16), (uint)u6|((uint)u7<<16));
    *reinterpret_cast<uint4*>(&s_p[(r<<10) + ((chunk^swz)<<3)]) = pk;
  }
  #pragma unroll
  for (int d=1; d<16; d<<=1) sum += __shfl_xor(sum, d);
  float inv = 1.f/sum;
  for (int cc=0; cc<8; ++cc){          // pass 3: write attn fp32, keep normalized bf16 in LDS
    int chunk = (cc<<4) + seg;
    uint4 lv = *reinterpret_cast<uint4*>(&s_p[(r<<10) + ((chunk^swz)<<3)]);
    float o0 = bf2f(lv.x&0xffff)*inv, o1 = bf2f(lv.x>>16)*inv;
    float o2 = bf2f(lv.y&0xffff)*inv, o3 = bf2f(lv.y>>16)*inv;
    float o4 = bf2f(lv.z&0xffff)*inv, o5 = bf2f(lv.z>>16)*inv;
    float o6 = bf2f(lv.w&0xffff)*inv, o7 = bf2f(lv.w>>16)*inv;
    *reinterpret_cast<float4*>(arow + (chunk<<3))     = make_float4(o0,o1,o2,o3);
    *reinterpret_cast<float4*>(arow + (chunk<<3) + 4) = make_float4(o4,o5,o6,o7);
    uint4 pk = make_uint4(packbf2(o0,o1), packbf2(o2,o3), packbf2(o4,o5), packbf2(o6,o7));
    *reinterpret_cast<uint4*>(&s_p[(r<<10) + ((chunk^swz)<<3)]) = pk;
  }
  __syncthreads();

  // ---- PV: out[32 q][64 d]; each wave computes 16q x 16d ----
  f32x4 o = {};
  const int ar = (wr<<4) + fl;
  const int aswz = (ar>>1)&7;
  for (int kt=0; kt<16; ++kt){
    #pragma unroll
    for (int s=0;s<2;++s){
      int chunk = (kt<<3) + (s<<2) + quad;
      bf16x8 af = *reinterpret_cast<const bf16x8*>(&s_p[(ar<<10) + ((chunk^aswz)<<3)]);
      bf16x8 bf = *reinterpret_cast<const bf16x8*>(
          vT + (((size_t)bh<<6) + (wc<<4) + fl)*1024 + (kt<<6) + (s<<5) + (quad<<3));
      o = MFMA16(af, bf, o);
    }
  }
  #pragma unroll
  for (int r4=0;r4<4;++r4){
    int row = (wr<<4) + (quad<<2) + r4;
    int col = (wc<<4) + fl;
    outc[((bS + q0 + row)<<9) + (h<<6) + col] = f2bf(o[r4]);
  }
}

extern "C" void kernel_launch(void* const* d_in, const int* in_sizes, int n_in,
                              void* d_out, int out_size, void* d_ws, size_t ws_size,
                              hipStream_t stream){
  (void)in_sizes; (void)n_in; (void)out_size; (void)ws_size;
  const float* q  = (const float*)d_in[0];
  const float* k  = (const float*)d_in[1];
  const float* v  = (const float*)d_in[2];
  const float* xd = (const float*)d_in[3];
  const float* Wq = (const float*)d_in[4];  const float* bq = (const float*)d_in[5];
  const float* Wk = (const float*)d_in[6];  const float* bk = (const float*)d_in[7];
  const float* Wv = (const float*)d_in[8];  const float* bv = (const float*)d_in[9];
  const float* Wx = (const float*)d_in[10]; const float* bx = (const float*)d_in[11];
  const float* Wo = (const float*)d_in[12]; const float* bo = (const float*)d_in[13];
  char* ws = (char*)d_ws;
  const size_t MB = 1u<<20;
  ushort* qp  = (ushort*)(ws);                 // [4096][512] bf16  (4 MB)
  ushort* kp  = (ushort*)(ws + 4*MB);
  ushort* vp  = (ushort*)(ws + 8*MB);
  ushort* vT  = (ushort*)(ws + 12*MB);         // [32*64][1024] bf16
  ushort* xb  = (ushort*)(ws + 16*MB);         // [4096][128] bf16  (1 MB)
  ushort* xl  = (ushort*)(ws + 17*MB);         // [4,8,1024,1024] bf16 (64 MB)
  ushort* oc  = (ushort*)(ws + 81*MB);         // [4096][512] bf16
  ushort* WqT = (ushort*)(ws + 85*MB);
  ushort* WkT = (ushort*)(ws + 85*MB + 1*524288);
  ushort* WvT = (ushort*)(ws + 85*MB + 2*524288);
  ushort* WoT = (ushort*)(ws + 85*MB + 3*524288);
  ushort* WxT = (ushort*)(ws + 85*MB + 4*524288);
  float* out0 = (float*)d_out;                 // [4,1024,512] fp32
  float* attn = (float*)d_out + 2097152;       // [4,8,1024,1024] fp32

  wt_kernel<<<dim3(8,8), 256, 0, stream>>>(Wq, WqT, 512, 512);
  wt_kernel<<<dim3(8,8), 256, 0, stream>>>(Wk, WkT, 512, 512);
  wt_kernel<<<dim3(8,8), 256, 0, stream>>>(Wv, WvT, 512, 512);
  wt_kernel<<<dim3(8,8), 256, 0, stream>>>(Wo, WoT, 512, 512);
  wt_kernel<<<dim3(2,8), 256, 0, stream>>>(Wx, WxT, 512, 128);

  gemm_bt<true,false><<<dim3(8,64), 256, 0, stream>>>(q, WqT, bq, qp, 4096, 512, 512);
  gemm_bt<true,false><<<dim3(8,64), 256, 0, stream>>>(k, WkT, bk, kp, 4096, 512, 512);
  gemm_bt<true,false><<<dim3(8,64), 256, 0, stream>>>(v, WvT, bv, vp, 4096, 512, 512);
  gemm_bt<false,false><<<dim3(2,64), 256, 0, stream>>>(qp, WxT, bx, xb, 4096, 128, 512);

  vtrans<<<dim3(16,32), 256, 0, stream>>>(vp, vT);
  xl_kernel<<<4096, 256, 0, stream>>>(xd, xb, xl);
  attn_kernel<<<dim3(32,8,4), 512, 0, stream>>>(qp, kp, vT, xl, attn, oc);
  gemm_bt<false,true><<<dim3(8,64), 256, 0, stream>>>(oc, WoT, bo, out0, 4096, 512, 512);
}